// Round 1
// baseline (230.632 us; speedup 1.0000x reference)
//
#include <hip/hip_runtime.h>

// B=4096, H=200, D=32, fp32. loss = mean_over_B( sum_{H,D} (p-t)^2 * (t!=0) )
// Output: (loss, loss) -> d_out has 2 floats.

#define BLOCK 256
#define GRID 2048

__global__ void wsl_init(double* ws) {
    if (blockIdx.x == 0 && threadIdx.x == 0) ws[0] = 0.0;
}

__global__ __launch_bounds__(BLOCK) void wsl_reduce(const float4* __restrict__ pred,
                                                    const float4* __restrict__ targ,
                                                    double* __restrict__ ws,
                                                    long n4) {
    long idx = (long)blockIdx.x * blockDim.x + threadIdx.x;
    long stride = (long)gridDim.x * blockDim.x;
    float acc = 0.0f;
    for (long i = idx; i < n4; i += stride) {
        float4 p = pred[i];
        float4 t = targ[i];
        float d0 = p.x - t.x;
        float d1 = p.y - t.y;
        float d2 = p.z - t.z;
        float d3 = p.w - t.w;
        acc += (t.x != 0.0f) ? d0 * d0 : 0.0f;
        acc += (t.y != 0.0f) ? d1 * d1 : 0.0f;
        acc += (t.z != 0.0f) ? d2 * d2 : 0.0f;
        acc += (t.w != 0.0f) ? d3 * d3 : 0.0f;
    }
    // wave-64 shuffle reduction
    #pragma unroll
    for (int off = 32; off > 0; off >>= 1)
        acc += __shfl_down(acc, off, 64);

    __shared__ float wsum[BLOCK / 64];
    int lane = threadIdx.x & 63;
    int wid  = threadIdx.x >> 6;
    if (lane == 0) wsum[wid] = acc;
    __syncthreads();
    if (threadIdx.x == 0) {
        float s = 0.0f;
        #pragma unroll
        for (int i = 0; i < BLOCK / 64; ++i) s += wsum[i];
        atomicAdd(ws, (double)s);  // device-scope, 2048 total -> negligible contention
    }
}

__global__ void wsl_finalize(const double* __restrict__ ws, float* __restrict__ out,
                             double inv_b) {
    if (blockIdx.x == 0 && threadIdx.x == 0) {
        float v = (float)(ws[0] * inv_b);
        out[0] = v;  // loss
        out[1] = v;  // a0_loss (same value)
    }
}

extern "C" void kernel_launch(void* const* d_in, const int* in_sizes, int n_in,
                              void* d_out, int out_size, void* d_ws, size_t ws_size,
                              hipStream_t stream) {
    const float4* pred = (const float4*)d_in[0];
    const float4* targ = (const float4*)d_in[1];
    float* out = (float*)d_out;
    double* ws = (double*)d_ws;

    const long n_elems = (long)in_sizes[0];      // 4096*200*32 = 26,214,400
    const long n4 = n_elems / 4;                 // divisible by 4
    const double inv_b = 1.0 / 4096.0;

    wsl_init<<<1, 64, 0, stream>>>(ws);
    wsl_reduce<<<GRID, BLOCK, 0, stream>>>(pred, targ, ws, n4);
    wsl_finalize<<<1, 64, 0, stream>>>(ws, out, inv_b);
}

// Round 4
// 223.583 us; speedup vs baseline: 1.0315x; 1.0315x over previous
//
#include <hip/hip_runtime.h>

// B=4096, H=200, D=32, fp32. loss = mean_over_B( sum_{H,D} (p-t)^2 * (t!=0) )
// Output: (loss, loss) -> d_out has 2 floats.
//
// n_elems = 26,214,400 = 6,553,600 float4. Each block covers 256 threads x
// UNROLL(4) float4 = 4096 elems -> exactly 6400 blocks, no remainder.

#define BLOCK 256
#define UNROLL 4

__global__ __launch_bounds__(BLOCK) void wsl_partials(const float4* __restrict__ pred,
                                                      const float4* __restrict__ targ,
                                                      float* __restrict__ partials,
                                                      long n4) {
    long base = (long)blockIdx.x * (BLOCK * UNROLL) + threadIdx.x;

    // Issue all 8 loads (4 pred + 4 targ) before any arithmetic -> 8 outstanding
    // 16B loads per lane. Static indices after unroll (no scratch spill).
    float4 p[UNROLL], t[UNROLL];
    #pragma unroll
    for (int k = 0; k < UNROLL; ++k) {
        long i = base + (long)k * BLOCK;
        p[k] = pred[i];
        t[k] = targ[i];
    }

    float acc = 0.0f;
    #pragma unroll
    for (int k = 0; k < UNROLL; ++k) {
        float d0 = p[k].x - t[k].x;
        float d1 = p[k].y - t[k].y;
        float d2 = p[k].z - t[k].z;
        float d3 = p[k].w - t[k].w;
        acc += (t[k].x != 0.0f) ? d0 * d0 : 0.0f;
        acc += (t[k].y != 0.0f) ? d1 * d1 : 0.0f;
        acc += (t[k].z != 0.0f) ? d2 * d2 : 0.0f;
        acc += (t[k].w != 0.0f) ? d3 * d3 : 0.0f;
    }

    // wave-64 shuffle reduction
    #pragma unroll
    for (int off = 32; off > 0; off >>= 1)
        acc += __shfl_down(acc, off, 64);

    __shared__ float wsum[BLOCK / 64];
    int lane = threadIdx.x & 63;
    int wid  = threadIdx.x >> 6;
    if (lane == 0) wsum[wid] = acc;
    __syncthreads();
    if (threadIdx.x == 0) {
        float s = 0.0f;
        #pragma unroll
        for (int i = 0; i < BLOCK / 64; ++i) s += wsum[i];
        partials[blockIdx.x] = s;  // no atomics, no init kernel needed
    }
}

__global__ __launch_bounds__(BLOCK) void wsl_final(const float* __restrict__ partials,
                                                   int nblocks,
                                                   float* __restrict__ out,
                                                   double inv_b) {
    double acc = 0.0;
    for (int i = threadIdx.x; i < nblocks; i += BLOCK)
        acc += (double)partials[i];

    #pragma unroll
    for (int off = 32; off > 0; off >>= 1)
        acc += __shfl_down(acc, off, 64);

    __shared__ double wsum[BLOCK / 64];
    int lane = threadIdx.x & 63;
    int wid  = threadIdx.x >> 6;
    if (lane == 0) wsum[wid] = acc;
    __syncthreads();
    if (threadIdx.x == 0) {
        double s = 0.0;
        #pragma unroll
        for (int i = 0; i < BLOCK / 64; ++i) s += wsum[i];
        float v = (float)(s * inv_b);
        out[0] = v;  // loss
        out[1] = v;  // a0_loss
    }
}

extern "C" void kernel_launch(void* const* d_in, const int* in_sizes, int n_in,
                              void* d_out, int out_size, void* d_ws, size_t ws_size,
                              hipStream_t stream) {
    const float4* pred = (const float4*)d_in[0];
    const float4* targ = (const float4*)d_in[1];
    float* out = (float*)d_out;
    float* partials = (float*)d_ws;

    const long n_elems = (long)in_sizes[0];          // 26,214,400
    const long n4 = n_elems / 4;                     // 6,553,600
    const int  nblocks = (int)(n4 / (BLOCK * UNROLL));  // 6400 exact

    wsl_partials<<<nblocks, BLOCK, 0, stream>>>(pred, targ, partials, n4);
    wsl_final<<<1, BLOCK, 0, stream>>>(partials, nblocks, out, 1.0 / 4096.0);
}

// Round 5
// 203.239 us; speedup vs baseline: 1.1348x; 1.1001x over previous
//
#include <hip/hip_runtime.h>

// B=4096, H=200, D=32, fp32. loss = mean_over_B( sum_{H,D} (p-t)^2 * (t!=0) )
// Output: (loss, loss) -> d_out has 2 floats.
//
// n4 = 6,553,600 float4-pairs. Grid 2560 x 256: each thread owns exactly
// ITERS(5) x 2 float4-pairs = 10, software-pipelined so ~8 nontemporal
// 16B loads stay in flight per lane for the kernel's whole life.

#define BLOCK 256
#define NBLK  2560
#define ITERS 5

typedef float f4 __attribute__((ext_vector_type(4)));

__device__ __forceinline__ float sq_masked(f4 p, f4 t) {
    float a = 0.0f;
    float d0 = p.x - t.x, d1 = p.y - t.y, d2 = p.z - t.z, d3 = p.w - t.w;
    a += (t.x != 0.0f) ? d0 * d0 : 0.0f;
    a += (t.y != 0.0f) ? d1 * d1 : 0.0f;
    a += (t.z != 0.0f) ? d2 * d2 : 0.0f;
    a += (t.w != 0.0f) ? d3 * d3 : 0.0f;
    return a;
}

__global__ __launch_bounds__(BLOCK) void wsl_partials(const f4* __restrict__ pred,
                                                      const f4* __restrict__ targ,
                                                      float* __restrict__ partials) {
    const long T = (long)NBLK * BLOCK;                   // 655,360 threads
    const long g = (long)blockIdx.x * BLOCK + threadIdx.x;

    // stage k covers [k*2T, (k+1)*2T); thread loads k*2T+g and k*2T+T+g
    f4 p0 = __builtin_nontemporal_load(&pred[g]);
    f4 p1 = __builtin_nontemporal_load(&pred[T + g]);
    f4 t0 = __builtin_nontemporal_load(&targ[g]);
    f4 t1 = __builtin_nontemporal_load(&targ[T + g]);

    float acc = 0.0f;
    #pragma unroll
    for (int k = 0; k < ITERS; ++k) {
        f4 q0, q1, u0, u1;
        if (k + 1 < ITERS) {                             // prefetch next stage
            long base = (long)(k + 1) * 2 * T + g;
            q0 = __builtin_nontemporal_load(&pred[base]);
            q1 = __builtin_nontemporal_load(&pred[base + T]);
            u0 = __builtin_nontemporal_load(&targ[base]);
            u1 = __builtin_nontemporal_load(&targ[base + T]);
        }
        acc += sq_masked(p0, t0);
        acc += sq_masked(p1, t1);
        if (k + 1 < ITERS) { p0 = q0; p1 = q1; t0 = u0; t1 = u1; }
    }

    // wave-64 shuffle reduction (once per wave for 640 B of lane data)
    #pragma unroll
    for (int off = 32; off > 0; off >>= 1)
        acc += __shfl_down(acc, off, 64);

    __shared__ float wsum[BLOCK / 64];
    int lane = threadIdx.x & 63;
    int wid  = threadIdx.x >> 6;
    if (lane == 0) wsum[wid] = acc;
    __syncthreads();
    if (threadIdx.x == 0) {
        float s = 0.0f;
        #pragma unroll
        for (int i = 0; i < BLOCK / 64; ++i) s += wsum[i];
        partials[blockIdx.x] = s;
    }
}

__global__ __launch_bounds__(BLOCK) void wsl_final(const float* __restrict__ partials,
                                                   int nblocks,
                                                   float* __restrict__ out,
                                                   double inv_b) {
    double acc = 0.0;
    for (int i = threadIdx.x; i < nblocks; i += BLOCK)
        acc += (double)partials[i];

    #pragma unroll
    for (int off = 32; off > 0; off >>= 1)
        acc += __shfl_down(acc, off, 64);

    __shared__ double wsum[BLOCK / 64];
    int lane = threadIdx.x & 63;
    int wid  = threadIdx.x >> 6;
    if (lane == 0) wsum[wid] = acc;
    __syncthreads();
    if (threadIdx.x == 0) {
        double s = 0.0;
        #pragma unroll
        for (int i = 0; i < BLOCK / 64; ++i) s += wsum[i];
        float v = (float)(s * inv_b);
        out[0] = v;  // loss
        out[1] = v;  // a0_loss
    }
}

extern "C" void kernel_launch(void* const* d_in, const int* in_sizes, int n_in,
                              void* d_out, int out_size, void* d_ws, size_t ws_size,
                              hipStream_t stream) {
    const f4* pred = (const f4*)d_in[0];
    const f4* targ = (const f4*)d_in[1];
    float* out = (float*)d_out;
    float* partials = (float*)d_ws;

    // n4 = 26,214,400/4 = 6,553,600 = NBLK*BLOCK*ITERS*2 exactly.
    wsl_partials<<<NBLK, BLOCK, 0, stream>>>(pred, targ, partials);
    wsl_final<<<1, BLOCK, 0, stream>>>(partials, NBLK, out, 1.0 / 4096.0);
}